// Round 5
// baseline (331.023 us; speedup 1.0000x reference)
//
#include <hip/hip_runtime.h>
#include <hip/hip_bf16.h>

typedef __attribute__((ext_vector_type(4))) float  f32x4;
typedef __attribute__((ext_vector_type(8))) short  short8;
typedef __attribute__((ext_vector_type(2))) float  flt2;
typedef long long ll;

__device__ __forceinline__ short f2bf(float f) {
    __hip_bfloat16 h = __float2bfloat16(f);
    short s; __builtin_memcpy(&s, &h, 2);
    return s;
}
__device__ __forceinline__ float bf2f(short s) {
    unsigned u = ((unsigned)(unsigned short)s) << 16;
    float f; __builtin_memcpy(&f, &u, 4);
    return f;
}
__device__ __forceinline__ void gload_lds16(const void* g, void* l) {
    __builtin_amdgcn_global_load_lds(
        (const __attribute__((address_space(1))) unsigned*)(g),
        (__attribute__((address_space(3))) unsigned*)(l),
        16, 0, 0);
}

// ---------------------------------------------------------------------------
// prep: convert/transpose weights to bf16 [k][co][ci]; also zero zrow.
// ---------------------------------------------------------------------------
__global__ void prep_kernel(const float* __restrict__ W1, const float* __restrict__ W2,
                            const float* __restrict__ W3, const float* __restrict__ W4,
                            const float* __restrict__ W5,
                            short* W1t, short* W2t, short* W3t, short* W4t, short* W5t) {
    int gid = blockIdx.x * 256 + threadIdx.x;
    if (gid < 32 * 64) {                       // W1t[co][e], e=2k+ci, pad e>=54
        int co = gid >> 6, e = gid & 63;
        float v = 0.f;
        if (e < 54) { int k = e >> 1, ci = e & 1; v = W1[(k * 2 + ci) * 32 + co]; }
        W1t[gid] = f2bf(v);
        return;
    }
    int g = gid - 32 * 64;
    if (g < 27 * 64 * 32) { int k = g / (64*32), r = g % (64*32), co = r >> 5, ci = r & 31;
        W2t[g] = f2bf(W2[((ll)k * 32 + ci) * 64 + co]); return; }
    g -= 27 * 64 * 32;
    if (g < 27 * 128 * 64) { int k = g / (128*64), r = g % (128*64), co = r >> 6, ci = r & 63;
        W3t[g] = f2bf(W3[((ll)k * 64 + ci) * 128 + co]); return; }
    g -= 27 * 128 * 64;
    if (g < 8 * 64 * 128) { int k = g / (64*128), r = g % (64*128), co = r >> 7, ci = r & 127;
        W4t[g] = f2bf(W4[((ll)k * 128 + ci) * 64 + co]); return; }
    g -= 8 * 64 * 128;
    if (g < 8 * 32 * 64) { int k = g / (32*64), r = g % (32*64), co = r >> 6, ci = r & 63;
        W5t[g] = f2bf(W5[((ll)k * 64 + ci) * 32 + co]); return; }
}

// ---------------------------------------------------------------------------
// conv1 as dense MFMA GEMM: A[r][e] = feats[nbr[e/2][r]][e&1] (K=54 pad 64)
// ---------------------------------------------------------------------------
__launch_bounds__(256)
__global__ void c1_kernel(const float* __restrict__ feats, const int* __restrict__ nbr,
                          const short* __restrict__ W1t, short* __restrict__ out, int N) {
    int tid = threadIdx.x, lane = tid & 63, wave = tid >> 6;
    int rb = blockIdx.x * 64 + wave * 16;
    int r = rb + (lane & 15);
    int rl = r < N ? r : N - 1;
    int seg = lane >> 4;
    f32x4 acc[2];
    acc[0] = (f32x4){0,0,0,0}; acc[1] = (f32x4){0,0,0,0};
    short8 a[2];
    #pragma unroll
    for (int kc = 0; kc < 2; ++kc) {
        #pragma unroll
        for (int j = 0; j < 4; ++j) {
            int k = kc * 16 + seg * 4 + j;
            flt2 f = (flt2){0.f, 0.f};
            if (k < 27) {
                int idx = nbr[(ll)k * N + rl];
                if (idx >= 0) f = *(const flt2*)(feats + 2 * (ll)idx);
            }
            a[kc][2*j]   = f2bf(f[0]);
            a[kc][2*j+1] = f2bf(f[1]);
        }
    }
    #pragma unroll
    for (int kc = 0; kc < 2; ++kc)
        #pragma unroll
        for (int c = 0; c < 2; ++c) {
            short8 b = *(const short8*)(W1t + (c*16 + (lane & 15)) * 64 + kc * 32 + seg * 8);
            acc[c] = __builtin_amdgcn_mfma_f32_16x16x32_bf16(a[kc], b, acc[c], 0, 0, 0);
        }
    int r0 = rb + seg * 4;
    #pragma unroll
    for (int c = 0; c < 2; ++c) {
        int col = c * 16 + (lane & 15);
        #pragma unroll
        for (int j = 0; j < 4; ++j)
            if (r0 + j < N) out[(ll)(r0 + j) * 32 + col] = f2bf(acc[c][j]);
    }
}

// ---------------------------------------------------------------------------
// Sparse MFMA conv. 64 rows x COLS per block (grid.y = COUTF/COLS), 4 waves
// x 16 rows. KB k-offsets staged per barrier period (double-buffered LDS);
// A/idx prefetched one period ahead; zero-row for missing neighbors.
// ---------------------------------------------------------------------------
template<int CIN, int COUTF, int COLS, int KB, int NK>
__launch_bounds__(256)
__global__ void msconv_kernel(const short* __restrict__ inb, const int* __restrict__ nbr,
                              const short* __restrict__ Wt, const short* __restrict__ zrow,
                              short* __restrict__ out, int N) {
    constexpr int KC = CIN / 32, NT = COLS / 16, NP = NK / KB;
    constexpr int CPK = COLS * CIN / 8;          // 16B chunks per k-tile
    constexpr int BIT = KB * CPK / 256;          // staging issues per thread
    __shared__ __align__(16) short lb[2][KB * COLS * CIN];

    const int tid = threadIdx.x, lane = tid & 63, wave = tid >> 6;
    const int seg = lane >> 4, l15 = lane & 15;
    const int cb = blockIdx.y * COLS;
    const int wrb = blockIdx.x * 64 + wave * 16;
    int rl = wrb + l15; if (rl >= N) rl = N - 1;

    auto stage = [&](int p, int buf) {
        #pragma unroll
        for (int it = 0; it < BIT; ++it) {
            int q = it * 256 + tid;
            int kk = q / CPK, rem = q % CPK;
            int co = rem % COLS, sg = (rem / COLS) & 3, kc = rem / (COLS * 4);
            gload_lds16(Wt + ((ll)(p * KB + kk) * COUTF + cb + co) * CIN + kc * 32 + sg * 8,
                        &lb[buf][q * 8]);
        }
    };
    auto ldIdx = [&](int (&ix)[KB], int p) {
        #pragma unroll
        for (int kk = 0; kk < KB; ++kk) ix[kk] = nbr[(ll)(p * KB + kk) * N + rl];
    };
    auto ldA = [&](short8 (&a)[KB][KC], const int (&ix)[KB]) {
        #pragma unroll
        for (int kk = 0; kk < KB; ++kk) {
            const short* base = (ix[kk] < 0) ? zrow : (inb + (ll)ix[kk] * CIN);
            #pragma unroll
            for (int kc = 0; kc < KC; ++kc)
                a[kk][kc] = *(const short8*)(base + kc * 32 + seg * 8);
        }
    };

    f32x4 acc[NT];
    #pragma unroll
    for (int c = 0; c < NT; ++c) acc[c] = (f32x4){0.f, 0.f, 0.f, 0.f};

    auto compute = [&](int buf, short8 (&a)[KB][KC]) {
        #pragma unroll
        for (int kk = 0; kk < KB; ++kk)
            #pragma unroll
            for (int kc = 0; kc < KC; ++kc)
                #pragma unroll
                for (int c = 0; c < NT; ++c) {
                    short8 b = *(const short8*)&lb[buf][kk * COLS * CIN
                                + ((kc * 4 + seg) * COLS + c * 16 + l15) * 8];
                    acc[c] = __builtin_amdgcn_mfma_f32_16x16x32_bf16(a[kk][kc], b, acc[c], 0, 0, 0);
                }
    };

    short8 aC[KB][KC], aN[KB][KC];
    int idx0[KB], idxN[KB];
    ldIdx(idx0, 0);
    stage(0, 0);
    ldA(aC, idx0);
    ldIdx(idxN, 1);
    __syncthreads();

    auto body = [&](int p, short8 (&cur)[KB][KC], short8 (&nxt)[KB][KC]) {
        if (p + 1 < NP) {
            stage(p + 1, (p + 1) & 1);
            ldA(nxt, idxN);
            if (p + 2 < NP) ldIdx(idxN, p + 2);
        }
        compute(p & 1, cur);
        __syncthreads();
    };
    for (int p = 0; p + 2 <= NP; p += 2) { body(p, aC, aN); body(p + 1, aN, aC); }
    if (NP & 1) body(NP - 1, aC, aN);

    #pragma unroll
    for (int c = 0; c < NT; ++c) {
        int col = cb + c * 16 + l15;
        #pragma unroll
        for (int j = 0; j < 4; ++j) {
            int rr = wrb + seg * 4 + j;
            if (rr < N) out[(ll)rr * COUTF + col] = f2bf(acc[c][j]);
        }
    }
}

// ---------------------------------------------------------------------------
// Decoder list build: count per offset, 64-padded prefix (+ per-block k), scatter.
// ---------------------------------------------------------------------------
__global__ void dcount_kernel(const int* __restrict__ poff, int* __restrict__ cnt, int N) {
    __shared__ int lc[8];
    if (threadIdx.x < 8) lc[threadIdx.x] = 0;
    __syncthreads();
    int r = blockIdx.x * 256 + threadIdx.x;
    if (r < N) atomicAdd(&lc[poff[r]], 1);
    __syncthreads();
    if (threadIdx.x < 8 && lc[threadIdx.x]) atomicAdd(&cnt[threadIdx.x], lc[threadIdx.x]);
}

__global__ void dprefix_kernel(const int* __restrict__ cnt, int* __restrict__ bases,
                               int* __restrict__ kofb) {
    __shared__ int base[9];
    if (threadIdx.x == 0) {
        int b = 0;
        for (int k = 0; k < 8; ++k) { base[k] = b; b += (cnt[k] + 63) & ~63; }
        base[8] = b;
        for (int k = 0; k < 9; ++k) bases[k] = base[k];
    }
    __syncthreads();
    int nb = base[8] >> 6;
    for (int i = threadIdx.x; i < nb; i += 256) {
        int rb = i << 6, k = 0;
        while (rb >= base[k + 1]) ++k;
        kofb[i] = k;
    }
}

__global__ void dscatter_kernel(const int* __restrict__ poff, const int* __restrict__ bases,
                                int* __restrict__ cur, int* __restrict__ perm, int N) {
    __shared__ int lc[8], lbs[8];
    if (threadIdx.x < 8) lc[threadIdx.x] = 0;
    __syncthreads();
    int r = blockIdx.x * 256 + threadIdx.x;
    int k = 0, myl = 0;
    if (r < N) { k = poff[r]; myl = atomicAdd(&lc[k], 1); }
    __syncthreads();
    if (threadIdx.x < 8) lbs[threadIdx.x] = atomicAdd(&cur[threadIdx.x], lc[threadIdx.x]);
    __syncthreads();
    if (r < N) perm[bases[k] + lbs[k] + myl] = r;
}

// ---------------------------------------------------------------------------
// Decoder gather-GEMM: each 64-row block handles rows of ONE offset k
// (perm list), A = in[pidx[perm[r]]], B = W[k] staged once in LDS.
// ---------------------------------------------------------------------------
template<int CIN, int COUT>
__launch_bounds__(256)
__global__ void gdec_kernel(const short* __restrict__ inb, const int* __restrict__ perm,
                            const int* __restrict__ kofb, const int* __restrict__ pidx,
                            const short* __restrict__ Wt, const short* __restrict__ zrow,
                            short* __restrict__ out) {
    constexpr int KC = CIN / 32, NT = COUT / 16;
    constexpr int CPK = COUT * CIN / 8, BIT = CPK / 256;
    __shared__ __align__(16) short lb[COUT * CIN];
    int k = kofb[blockIdx.x];
    if (k < 0) return;
    const int tid = threadIdx.x, lane = tid & 63, wave = tid >> 6;
    const int seg = lane >> 4, l15 = lane & 15;
    const int wrb = blockIdx.x * 64 + wave * 16;
    int rl = wrb + l15;
    int pr = perm[rl];
    int idx = pr < 0 ? -1 : pidx[pr];

    #pragma unroll
    for (int it = 0; it < BIT; ++it) {
        int q = it * 256 + tid;
        int co = q % COUT, sg = (q / COUT) & 3, kc = q / (COUT * 4);
        gload_lds16(Wt + ((ll)k * COUT + co) * CIN + kc * 32 + sg * 8, &lb[q * 8]);
    }
    short8 a[KC];
    const short* base = (idx < 0) ? zrow : (inb + (ll)idx * CIN);
    #pragma unroll
    for (int kc = 0; kc < KC; ++kc)
        a[kc] = *(const short8*)(base + kc * 32 + seg * 8);

    f32x4 acc[NT];
    #pragma unroll
    for (int c = 0; c < NT; ++c) acc[c] = (f32x4){0.f, 0.f, 0.f, 0.f};
    __syncthreads();
    #pragma unroll
    for (int kc = 0; kc < KC; ++kc)
        #pragma unroll
        for (int c = 0; c < NT; ++c) {
            short8 b = *(const short8*)&lb[((kc * 4 + seg) * COUT + c * 16 + l15) * 8];
            acc[c] = __builtin_amdgcn_mfma_f32_16x16x32_bf16(a[kc], b, acc[c], 0, 0, 0);
        }
    #pragma unroll
    for (int j = 0; j < 4; ++j) {
        int prs = __shfl(pr, seg * 4 + j, 64);
        if (prs >= 0) {
            #pragma unroll
            for (int c = 0; c < NT; ++c)
                out[(ll)prs * COUT + c * 16 + l15] = f2bf(acc[c][j]);
        }
    }
}

// ---------------------------------------------------------------------------
// BN stats partials (deterministic), reduce, BN+ReLU, final out.
// ---------------------------------------------------------------------------
template<int C>
__global__ void statsp_kernel(const short* __restrict__ x, float* __restrict__ part, int N) {
    constexpr int LPR = C / 8;
    constexpr int RPB = 256 / LPR;
    int cl = threadIdx.x % LPR, r0 = threadIdx.x / LPR;
    float s[8] = {0,0,0,0,0,0,0,0}, q[8] = {0,0,0,0,0,0,0,0};
    for (ll row = (ll)blockIdx.x * RPB + r0; row < N; row += (ll)gridDim.x * RPB) {
        short8 v = *(const short8*)(x + row * C + cl * 8);
        #pragma unroll
        for (int j = 0; j < 8; ++j) { float f = bf2f(v[j]); s[j] += f; q[j] += f * f; }
    }
    __shared__ float ls[256][8], lq[256][8];
    #pragma unroll
    for (int j = 0; j < 8; ++j) { ls[threadIdx.x][j] = s[j]; lq[threadIdx.x][j] = q[j]; }
    __syncthreads();
    for (int str = 128; str >= LPR; str >>= 1) {
        if (threadIdx.x < str) {
            #pragma unroll
            for (int j = 0; j < 8; ++j) {
                ls[threadIdx.x][j] += ls[threadIdx.x + str][j];
                lq[threadIdx.x][j] += lq[threadIdx.x + str][j];
            }
        }
        __syncthreads();
    }
    if (threadIdx.x < LPR) {
        #pragma unroll
        for (int j = 0; j < 8; ++j) {
            part[(ll)blockIdx.x * 2 * C + threadIdx.x * 8 + j]     = ls[threadIdx.x][j];
            part[(ll)blockIdx.x * 2 * C + C + threadIdx.x * 8 + j] = lq[threadIdx.x][j];
        }
    }
}

__global__ void red_kernel(const float* __restrict__ part, const float* __restrict__ g,
                           const float* __restrict__ bb, float* __restrict__ A,
                           float* __restrict__ B, int C, int N) {
    int c = blockIdx.x;
    __shared__ float ls[256], lq[256];
    ls[threadIdx.x] = part[(ll)threadIdx.x * 2 * C + c];
    lq[threadIdx.x] = part[(ll)threadIdx.x * 2 * C + C + c];
    __syncthreads();
    for (int str = 128; str >= 1; str >>= 1) {
        if (threadIdx.x < str) {
            ls[threadIdx.x] += ls[threadIdx.x + str];
            lq[threadIdx.x] += lq[threadIdx.x + str];
        }
        __syncthreads();
    }
    if (threadIdx.x == 0) {
        float inv = 1.0f / (float)N;
        float mu = ls[0] * inv, var = lq[0] * inv - mu * mu;
        float a = g[c] * rsqrtf(var + 1e-5f);
        A[c] = a; B[c] = bb[c] - mu * a;
    }
}

template<int C>
__global__ void bnrelu_kernel(const short* __restrict__ x, const float* __restrict__ A,
                              const float* __restrict__ B, short* __restrict__ out, int N) {
    constexpr int CPR = C / 8;
    int i = blockIdx.x * 256 + threadIdx.x;
    if (i >= N * CPR) return;
    int r = i / CPR, ch = i - r * CPR;
    short8 v = *(const short8*)(x + (ll)r * C + ch * 8);
    short8 o;
    #pragma unroll
    for (int j = 0; j < 8; ++j) {
        int c = ch * 8 + j;
        float y = fmaf(bf2f(v[j]), A[c], B[c]);
        o[j] = f2bf(y > 0.f ? y : 0.f);
    }
    *(short8*)(out + (ll)r * C + ch * 8) = o;
}

__global__ void outk_kernel(const short* __restrict__ z, const float* __restrict__ A,
                            const float* __restrict__ B, const float* __restrict__ Wout,
                            float* __restrict__ out, int N) {
    __shared__ float w[64], sa[32], sb[32];
    if (threadIdx.x < 64) w[threadIdx.x] = Wout[threadIdx.x];
    if (threadIdx.x < 32) { sa[threadIdx.x] = A[threadIdx.x]; sb[threadIdx.x] = B[threadIdx.x]; }
    __syncthreads();
    int r = blockIdx.x * 256 + threadIdx.x;
    if (r >= N) return;
    const short* zp = z + (ll)r * 32;
    float o0 = 0.f, o1 = 0.f;
    #pragma unroll
    for (int s4 = 0; s4 < 4; ++s4) {
        short8 v = *(const short8*)(zp + s4 * 8);
        #pragma unroll
        for (int j = 0; j < 8; ++j) {
            int c = s4 * 8 + j;
            float y = fmaf(bf2f(v[j]), sa[c], sb[c]);
            y = y > 0.f ? y : 0.f;
            o0 = fmaf(y, w[2*c], o0);
            o1 = fmaf(y, w[2*c+1], o1);
        }
    }
    out[(ll)r * 2]     = o0;
    out[(ll)r * 2 + 1] = o1;
}

extern "C" void kernel_launch(void* const* d_in, const int* in_sizes, int n_in,
                              void* d_out, int out_size, void* d_ws, size_t ws_size,
                              hipStream_t stream) {
    const float* feats = (const float*)d_in[0];
    const float* W1 = (const float*)d_in[1];
    const float* W2 = (const float*)d_in[2];
    const float* W3 = (const float*)d_in[3];
    const float* W4 = (const float*)d_in[4];
    const float* W5 = (const float*)d_in[5];
    const float* Wout = (const float*)d_in[6];
    const float* g1 = (const float*)d_in[7],  *b1 = (const float*)d_in[8];
    const float* g2 = (const float*)d_in[9],  *b2 = (const float*)d_in[10];
    const float* g3 = (const float*)d_in[11], *b3 = (const float*)d_in[12];
    const float* g4 = (const float*)d_in[13], *b4 = (const float*)d_in[14];
    const float* g5 = (const float*)d_in[15], *b5 = (const float*)d_in[16];
    const int* nbr0 = (const int*)d_in[17];
    const int* nbr1 = (const int*)d_in[18];
    const int* nbr2 = (const int*)d_in[19];
    const int* up1_idx = (const int*)d_in[20];
    const int* up1_off = (const int*)d_in[21];
    const int* up0_idx = (const int*)d_in[22];
    const int* up0_off = (const int*)d_in[23];

    const int N0 = in_sizes[0] / 2;
    const int N1 = in_sizes[20];
    const int N2 = in_sizes[19] / 27;

    char* cur = (char*)d_ws;
    auto alloc = [&](size_t bytes) { char* p = cur; cur += (bytes + 255) & ~255ULL; return p; };
    auto cdiv = [](ll a, ll b) { return (int)((a + b - 1) / b); };

    // stats block: 640 floats BN coeffs | zrow @+2560 (512B) | cnt/cur/bases
    float* stats = (float*)alloc(4096);
    float* A1 = stats,       *B1c = stats + 32;
    float* A2 = stats + 64,  *B2c = stats + 128;
    float* A3 = stats + 192, *B3c = stats + 320;
    float* A4 = stats + 448, *B4c = stats + 512;
    float* A5 = stats + 576, *B5c = stats + 608;
    short* zrow  = (short*)((char*)stats + 2560);   // 256 bf16 zeros
    int*   cnt4  = (int*)((char*)stats + 3072);     // 8
    int*   cur4  = (int*)((char*)stats + 3104);     // 8
    int*   cnt5  = (int*)((char*)stats + 3136);     // 8
    int*   cur5  = (int*)((char*)stats + 3168);     // 8
    int*   bas4  = (int*)((char*)stats + 3200);     // 9
    int*   bas5  = (int*)((char*)stats + 3264);     // 9

    float* part = (float*)alloc(256 * 256 * 4);

    size_t zmax = (size_t)N1 * 64;
    if ((size_t)N0 * 32  > zmax) zmax = (size_t)N0 * 32;
    if ((size_t)N2 * 128 > zmax) zmax = (size_t)N2 * 128;
    short* zb  = (short*)alloc(zmax * 2);
    short* e1b = (short*)alloc((size_t)N0 * 32 * 2);
    short* e2b = (short*)alloc((size_t)N1 * 64 * 2);
    short* e3b = (short*)alloc((size_t)N2 * 128 * 2);
    short* d2b = (short*)alloc((size_t)N1 * 64 * 2);
    short* W1t = (short*)alloc(32 * 64 * 2);
    short* W2t = (short*)alloc((size_t)27 * 64 * 32 * 2);
    short* W3t = (short*)alloc((size_t)27 * 128 * 64 * 2);
    short* W4t = (short*)alloc((size_t)8 * 64 * 128 * 2);
    short* W5t = (short*)alloc((size_t)8 * 32 * 64 * 2);

    const int gridL4 = cdiv((ll)N1 + 512, 64);
    const int gridL5 = cdiv((ll)N0 + 512, 64);
    char* pstart = cur;
    int* perm4 = (int*)alloc((size_t)gridL4 * 64 * 4);
    int* kofb4 = (int*)alloc((size_t)gridL4 * 4);
    int* perm5 = (int*)alloc((size_t)gridL5 * 64 * 4);
    int* kofb5 = (int*)alloc((size_t)gridL5 * 4);
    size_t plen = (size_t)(cur - pstart);

    // zero zrow + counters (640B); 0xFF perm/kofb (-1 sentinel)
    hipMemsetAsync((char*)stats + 2560, 0, 640, stream);
    hipMemsetAsync(pstart, 0xFF, plen, stream);

    prep_kernel<<<cdiv(2048 + 55296 + 221184 + 65536 + 16384, 256), 256, 0, stream>>>(
        W1, W2, W3, W4, W5, W1t, W2t, W3t, W4t, W5t);

    // decoder permutation lists (inputs only — build up front)
    dcount_kernel<<<cdiv(N1, 256), 256, 0, stream>>>(up1_off, cnt4, N1);
    dprefix_kernel<<<1, 256, 0, stream>>>(cnt4, bas4, kofb4);
    dscatter_kernel<<<cdiv(N1, 256), 256, 0, stream>>>(up1_off, bas4, cur4, perm4, N1);
    dcount_kernel<<<cdiv(N0, 256), 256, 0, stream>>>(up0_off, cnt5, N0);
    dprefix_kernel<<<1, 256, 0, stream>>>(cnt5, bas5, kofb5);
    dscatter_kernel<<<cdiv(N0, 256), 256, 0, stream>>>(up0_off, bas5, cur5, perm5, N0);

    // L1: conv(2->32)
    c1_kernel<<<cdiv(N0, 64), 256, 0, stream>>>(feats, nbr0, W1t, zb, N0);
    statsp_kernel<32><<<256, 256, 0, stream>>>(zb, part, N0);
    red_kernel<<<32, 256, 0, stream>>>(part, g1, b1, A1, B1c, 32, N0);
    bnrelu_kernel<32><<<cdiv((ll)N0 * 4, 256), 256, 0, stream>>>(zb, A1, B1c, e1b, N0);

    // L2: conv(32->64), 64 cols, KB=3
    msconv_kernel<32, 64, 64, 3, 27><<<dim3(cdiv(N1, 64), 1), 256, 0, stream>>>(
        e1b, nbr1, W2t, zrow, zb, N1);
    statsp_kernel<64><<<256, 256, 0, stream>>>(zb, part, N1);
    red_kernel<<<64, 256, 0, stream>>>(part, g2, b2, A2, B2c, 64, N1);
    bnrelu_kernel<64><<<cdiv((ll)N1 * 8, 256), 256, 0, stream>>>(zb, A2, B2c, e2b, N1);

    // L3: conv(64->128), 32-col split x4, KB=3
    msconv_kernel<64, 128, 32, 3, 27><<<dim3(cdiv(N2, 64), 4), 256, 0, stream>>>(
        e2b, nbr2, W3t, zrow, zb, N2);
    statsp_kernel<128><<<256, 256, 0, stream>>>(zb, part, N2);
    red_kernel<<<128, 256, 0, stream>>>(part, g3, b3, A3, B3c, 128, N2);
    bnrelu_kernel<128><<<cdiv((ll)N2 * 16, 256), 256, 0, stream>>>(zb, A3, B3c, e3b, N2);

    // L4: upconv(128->64) as permuted gather-GEMM
    gdec_kernel<128, 64><<<gridL4, 256, 0, stream>>>(e3b, perm4, kofb4, up1_idx, W4t, zrow, zb);
    statsp_kernel<64><<<256, 256, 0, stream>>>(zb, part, N1);
    red_kernel<<<64, 256, 0, stream>>>(part, g4, b4, A4, B4c, 64, N1);
    bnrelu_kernel<64><<<cdiv((ll)N1 * 8, 256), 256, 0, stream>>>(zb, A4, B4c, d2b, N1);

    // L5: upconv(64->32) as permuted gather-GEMM + fused BN+ReLU+1x1
    gdec_kernel<64, 32><<<gridL5, 256, 0, stream>>>(d2b, perm5, kofb5, up0_idx, W5t, zrow, zb);
    statsp_kernel<32><<<256, 256, 0, stream>>>(zb, part, N0);
    red_kernel<<<32, 256, 0, stream>>>(part, g5, b5, A5, B5c, 32, N0);
    outk_kernel<<<cdiv(N0, 256), 256, 0, stream>>>(zb, A5, B5c, Wout, (float*)d_out, N0);
}

// Round 6
// 316.750 us; speedup vs baseline: 1.0451x; 1.0451x over previous
//
#include <hip/hip_runtime.h>
#include <hip/hip_bf16.h>

typedef __attribute__((ext_vector_type(4))) float  f32x4;
typedef __attribute__((ext_vector_type(8))) short  short8;
typedef __attribute__((ext_vector_type(2))) float  flt2;
typedef long long ll;

__device__ __forceinline__ short f2bf(float f) {
    __hip_bfloat16 h = __float2bfloat16(f);
    short s; __builtin_memcpy(&s, &h, 2);
    return s;
}
__device__ __forceinline__ float bf2f(short s) {
    unsigned u = ((unsigned)(unsigned short)s) << 16;
    float f; __builtin_memcpy(&f, &u, 4);
    return f;
}
__device__ __forceinline__ void gload_lds16(const void* g, void* l) {
    __builtin_amdgcn_global_load_lds(
        (const __attribute__((address_space(1))) unsigned*)(g),
        (__attribute__((address_space(3))) unsigned*)(l),
        16, 0, 0);
}

// ---------------------------------------------------------------------------
// prep: convert/transpose weights to bf16 [k][co][ci].
// ---------------------------------------------------------------------------
__global__ void prep_kernel(const float* __restrict__ W1, const float* __restrict__ W2,
                            const float* __restrict__ W3, const float* __restrict__ W4,
                            const float* __restrict__ W5,
                            short* W1t, short* W2t, short* W3t, short* W4t, short* W5t) {
    int gid = blockIdx.x * 256 + threadIdx.x;
    if (gid < 32 * 64) {                       // W1t[co][e], e=2k+ci, pad e>=54
        int co = gid >> 6, e = gid & 63;
        float v = 0.f;
        if (e < 54) { int k = e >> 1, ci = e & 1; v = W1[(k * 2 + ci) * 32 + co]; }
        W1t[gid] = f2bf(v);
        return;
    }
    int g = gid - 32 * 64;
    if (g < 27 * 64 * 32) { int k = g / (64*32), r = g % (64*32), co = r >> 5, ci = r & 31;
        W2t[g] = f2bf(W2[((ll)k * 32 + ci) * 64 + co]); return; }
    g -= 27 * 64 * 32;
    if (g < 27 * 128 * 64) { int k = g / (128*64), r = g % (128*64), co = r >> 6, ci = r & 63;
        W3t[g] = f2bf(W3[((ll)k * 64 + ci) * 128 + co]); return; }
    g -= 27 * 128 * 64;
    if (g < 8 * 64 * 128) { int k = g / (64*128), r = g % (64*128), co = r >> 7, ci = r & 127;
        W4t[g] = f2bf(W4[((ll)k * 128 + ci) * 64 + co]); return; }
    g -= 8 * 64 * 128;
    if (g < 8 * 32 * 64) { int k = g / (32*64), r = g % (32*64), co = r >> 6, ci = r & 63;
        W5t[g] = f2bf(W5[((ll)k * 64 + ci) * 32 + co]); return; }
}

// ---------------------------------------------------------------------------
// conv1 as dense MFMA GEMM: A[r][e] = feats[nbr[e/2][r]][e&1] (K=54 pad 64)
// ---------------------------------------------------------------------------
__launch_bounds__(256)
__global__ void c1_kernel(const float* __restrict__ feats, const int* __restrict__ nbr,
                          const short* __restrict__ W1t, short* __restrict__ out, int N) {
    int tid = threadIdx.x, lane = tid & 63, wave = tid >> 6;
    int rb = blockIdx.x * 64 + wave * 16;
    int r = rb + (lane & 15);
    int rl = r < N ? r : N - 1;
    int seg = lane >> 4;
    f32x4 acc[2];
    acc[0] = (f32x4){0,0,0,0}; acc[1] = (f32x4){0,0,0,0};
    short8 a[2];
    #pragma unroll
    for (int kc = 0; kc < 2; ++kc) {
        #pragma unroll
        for (int j = 0; j < 4; ++j) {
            int k = kc * 16 + seg * 4 + j;
            flt2 f = (flt2){0.f, 0.f};
            if (k < 27) {
                int idx = nbr[(ll)k * N + rl];
                if (idx >= 0) f = *(const flt2*)(feats + 2 * (ll)idx);
            }
            a[kc][2*j]   = f2bf(f[0]);
            a[kc][2*j+1] = f2bf(f[1]);
        }
    }
    #pragma unroll
    for (int kc = 0; kc < 2; ++kc)
        #pragma unroll
        for (int c = 0; c < 2; ++c) {
            short8 b = *(const short8*)(W1t + (c*16 + (lane & 15)) * 64 + kc * 32 + seg * 8);
            acc[c] = __builtin_amdgcn_mfma_f32_16x16x32_bf16(a[kc], b, acc[c], 0, 0, 0);
        }
    int r0 = rb + seg * 4;
    #pragma unroll
    for (int c = 0; c < 2; ++c) {
        int col = c * 16 + (lane & 15);
        #pragma unroll
        for (int j = 0; j < 4; ++j)
            if (r0 + j < N) out[(ll)(r0 + j) * 32 + col] = f2bf(acc[c][j]);
    }
}

// ---------------------------------------------------------------------------
// Sparse MFMA conv. Block = 64*RG rows x COLS (grid.y = COUTF/COLS), 4 waves,
// each wave 16*RG rows. KB k-offsets per barrier period, double-buffered LDS;
// B ds_reads reused across RG rowgroups; A regs + idx prefetched 1 period
// ahead; zero-row for missing neighbors. One barrier per period.
// ---------------------------------------------------------------------------
template<int CIN, int COUTF, int COLS, int RG, int KB, int NK>
__launch_bounds__(256, 4)
__global__ void msconv_kernel(const short* __restrict__ inb, const int* __restrict__ nbr,
                              const short* __restrict__ Wt, const short* __restrict__ zrow,
                              short* __restrict__ out, int N) {
    constexpr int KC = CIN / 32, NT = COLS / 16, NP = NK / KB;
    constexpr int CPK = COLS * CIN / 8;          // 16B chunks per k-tile
    constexpr int BIT = KB * CPK / 256;          // staging issues per thread
    __shared__ __align__(16) short lb[2][KB * COLS * CIN];

    const int tid = threadIdx.x, lane = tid & 63, wave = tid >> 6;
    const int seg = lane >> 4, l15 = lane & 15;
    const int cb = blockIdx.y * COLS;
    const int wrb = blockIdx.x * (64 * RG) + wave * (16 * RG);
    int rl[RG];
    #pragma unroll
    for (int rg = 0; rg < RG; ++rg) {
        rl[rg] = wrb + rg * 16 + l15;
        if (rl[rg] >= N) rl[rg] = N - 1;
    }

    auto stage = [&](int p, int buf) {
        #pragma unroll
        for (int it = 0; it < BIT; ++it) {
            int q = it * 256 + tid;
            int kk = q / CPK, rem = q % CPK;
            int co = rem % COLS, sg = (rem / COLS) & 3, kc = rem / (COLS * 4);
            gload_lds16(Wt + ((ll)(p * KB + kk) * COUTF + cb + co) * CIN + kc * 32 + sg * 8,
                        &lb[buf][q * 8]);
        }
    };

    int idxN[KB][RG];
    auto ldIdx = [&](int p) {
        #pragma unroll
        for (int kk = 0; kk < KB; ++kk)
            #pragma unroll
            for (int rg = 0; rg < RG; ++rg)
                idxN[kk][rg] = nbr[(ll)(p * KB + kk) * N + rl[rg]];
    };
    auto ldA = [&](short8 (&a)[KB][RG][KC]) {
        #pragma unroll
        for (int kk = 0; kk < KB; ++kk)
            #pragma unroll
            for (int rg = 0; rg < RG; ++rg) {
                const short* base = (idxN[kk][rg] < 0) ? zrow : (inb + (ll)idxN[kk][rg] * CIN);
                #pragma unroll
                for (int kc = 0; kc < KC; ++kc)
                    a[kk][rg][kc] = *(const short8*)(base + kc * 32 + seg * 8);
            }
    };

    f32x4 acc[RG][NT];
    #pragma unroll
    for (int rg = 0; rg < RG; ++rg)
        #pragma unroll
        for (int c = 0; c < NT; ++c) acc[rg][c] = (f32x4){0.f, 0.f, 0.f, 0.f};

    auto compute = [&](int buf, short8 (&a)[KB][RG][KC]) {
        #pragma unroll
        for (int kk = 0; kk < KB; ++kk)
            #pragma unroll
            for (int kc = 0; kc < KC; ++kc)
                #pragma unroll
                for (int c = 0; c < NT; ++c) {
                    short8 b = *(const short8*)&lb[buf][kk * COLS * CIN
                                + ((kc * 4 + seg) * COLS + c * 16 + l15) * 8];
                    #pragma unroll
                    for (int rg = 0; rg < RG; ++rg)
                        acc[rg][c] = __builtin_amdgcn_mfma_f32_16x16x32_bf16(
                            a[kk][rg][kc], b, acc[rg][c], 0, 0, 0);
                }
    };

    short8 aC[KB][RG][KC], aN[KB][RG][KC];
    ldIdx(0);
    stage(0, 0);
    ldA(aC);
    ldIdx(1);
    __syncthreads();

    auto body = [&](int p, short8 (&cur)[KB][RG][KC], short8 (&nxt)[KB][RG][KC]) {
        if (p + 1 < NP) {
            stage(p + 1, (p + 1) & 1);
            ldA(nxt);
            if (p + 2 < NP) ldIdx(p + 2);
        }
        compute(p & 1, cur);
        __syncthreads();
    };
    for (int p = 0; p + 2 <= NP; p += 2) { body(p, aC, aN); body(p + 1, aN, aC); }
    if (NP & 1) body(NP - 1, aC, aN);

    #pragma unroll
    for (int rg = 0; rg < RG; ++rg)
        #pragma unroll
        for (int c = 0; c < NT; ++c) {
            int col = cb + c * 16 + l15;
            #pragma unroll
            for (int j = 0; j < 4; ++j) {
                int rr = wrb + rg * 16 + seg * 4 + j;
                if (rr < N) out[(ll)rr * COUTF + col] = f2bf(acc[rg][c][j]);
            }
        }
}

// ---------------------------------------------------------------------------
// Decoder list build: count per offset, 64-padded prefix (+ per-block k), scatter.
// ---------------------------------------------------------------------------
__global__ void dcount_kernel(const int* __restrict__ poff, int* __restrict__ cnt, int N) {
    __shared__ int lc[8];
    if (threadIdx.x < 8) lc[threadIdx.x] = 0;
    __syncthreads();
    int r = blockIdx.x * 256 + threadIdx.x;
    if (r < N) atomicAdd(&lc[poff[r]], 1);
    __syncthreads();
    if (threadIdx.x < 8 && lc[threadIdx.x]) atomicAdd(&cnt[threadIdx.x], lc[threadIdx.x]);
}

__global__ void dprefix_kernel(const int* __restrict__ cnt, int* __restrict__ bases,
                               int* __restrict__ kofb) {
    __shared__ int base[9];
    if (threadIdx.x == 0) {
        int b = 0;
        for (int k = 0; k < 8; ++k) { base[k] = b; b += (cnt[k] + 63) & ~63; }
        base[8] = b;
        for (int k = 0; k < 9; ++k) bases[k] = base[k];
    }
    __syncthreads();
    int nb = base[8] >> 6;
    for (int i = threadIdx.x; i < nb; i += 256) {
        int rb = i << 6, k = 0;
        while (rb >= base[k + 1]) ++k;
        kofb[i] = k;
    }
}

__global__ void dscatter_kernel(const int* __restrict__ poff, const int* __restrict__ bases,
                                int* __restrict__ cur, int* __restrict__ perm, int N) {
    __shared__ int lc[8], lbs[8];
    if (threadIdx.x < 8) lc[threadIdx.x] = 0;
    __syncthreads();
    int r = blockIdx.x * 256 + threadIdx.x;
    int k = 0, myl = 0;
    if (r < N) { k = poff[r]; myl = atomicAdd(&lc[k], 1); }
    __syncthreads();
    if (threadIdx.x < 8) lbs[threadIdx.x] = atomicAdd(&cur[threadIdx.x], lc[threadIdx.x]);
    __syncthreads();
    if (r < N) perm[bases[k] + lbs[k] + myl] = r;
}

// ---------------------------------------------------------------------------
// Decoder gather-GEMM: each 64-row block handles rows of ONE offset k
// (perm list), A = in[pidx[perm[r]]], B = W[k] staged once in LDS.
// ---------------------------------------------------------------------------
template<int CIN, int COUT>
__launch_bounds__(256)
__global__ void gdec_kernel(const short* __restrict__ inb, const int* __restrict__ perm,
                            const int* __restrict__ kofb, const int* __restrict__ pidx,
                            const short* __restrict__ Wt, const short* __restrict__ zrow,
                            short* __restrict__ out) {
    constexpr int KC = CIN / 32, NT = COUT / 16;
    constexpr int CPK = COUT * CIN / 8, BIT = CPK / 256;
    __shared__ __align__(16) short lb[COUT * CIN];
    int k = kofb[blockIdx.x];
    if (k < 0) return;
    const int tid = threadIdx.x, lane = tid & 63, wave = tid >> 6;
    const int seg = lane >> 4, l15 = lane & 15;
    const int wrb = blockIdx.x * 64 + wave * 16;
    int rl = wrb + l15;
    int pr = perm[rl];
    int idx = pr < 0 ? -1 : pidx[pr];

    #pragma unroll
    for (int it = 0; it < BIT; ++it) {
        int q = it * 256 + tid;
        int co = q % COUT, sg = (q / COUT) & 3, kc = q / (COUT * 4);
        gload_lds16(Wt + ((ll)k * COUT + co) * CIN + kc * 32 + sg * 8, &lb[q * 8]);
    }
    short8 a[KC];
    const short* base = (idx < 0) ? zrow : (inb + (ll)idx * CIN);
    #pragma unroll
    for (int kc = 0; kc < KC; ++kc)
        a[kc] = *(const short8*)(base + kc * 32 + seg * 8);

    f32x4 acc[NT];
    #pragma unroll
    for (int c = 0; c < NT; ++c) acc[c] = (f32x4){0.f, 0.f, 0.f, 0.f};
    __syncthreads();
    #pragma unroll
    for (int kc = 0; kc < KC; ++kc)
        #pragma unroll
        for (int c = 0; c < NT; ++c) {
            short8 b = *(const short8*)&lb[((kc * 4 + seg) * COUT + c * 16 + l15) * 8];
            acc[c] = __builtin_amdgcn_mfma_f32_16x16x32_bf16(a[kc], b, acc[c], 0, 0, 0);
        }
    #pragma unroll
    for (int j = 0; j < 4; ++j) {
        int prs = __shfl(pr, seg * 4 + j, 64);
        if (prs >= 0) {
            #pragma unroll
            for (int c = 0; c < NT; ++c)
                out[(ll)prs * COUT + c * 16 + l15] = f2bf(acc[c][j]);
        }
    }
}

// ---------------------------------------------------------------------------
// BN stats partials (deterministic), reduce, BN+ReLU, final out.
// ---------------------------------------------------------------------------
template<int C>
__global__ void statsp_kernel(const short* __restrict__ x, float* __restrict__ part, int N) {
    constexpr int LPR = C / 8;
    constexpr int RPB = 256 / LPR;
    int cl = threadIdx.x % LPR, r0 = threadIdx.x / LPR;
    float s[8] = {0,0,0,0,0,0,0,0}, q[8] = {0,0,0,0,0,0,0,0};
    for (ll row = (ll)blockIdx.x * RPB + r0; row < N; row += (ll)gridDim.x * RPB) {
        short8 v = *(const short8*)(x + row * C + cl * 8);
        #pragma unroll
        for (int j = 0; j < 8; ++j) { float f = bf2f(v[j]); s[j] += f; q[j] += f * f; }
    }
    __shared__ float ls[256][8], lq[256][8];
    #pragma unroll
    for (int j = 0; j < 8; ++j) { ls[threadIdx.x][j] = s[j]; lq[threadIdx.x][j] = q[j]; }
    __syncthreads();
    for (int str = 128; str >= LPR; str >>= 1) {
        if (threadIdx.x < str) {
            #pragma unroll
            for (int j = 0; j < 8; ++j) {
                ls[threadIdx.x][j] += ls[threadIdx.x + str][j];
                lq[threadIdx.x][j] += lq[threadIdx.x + str][j];
            }
        }
        __syncthreads();
    }
    if (threadIdx.x < LPR) {
        #pragma unroll
        for (int j = 0; j < 8; ++j) {
            part[(ll)blockIdx.x * 2 * C + threadIdx.x * 8 + j]     = ls[threadIdx.x][j];
            part[(ll)blockIdx.x * 2 * C + C + threadIdx.x * 8 + j] = lq[threadIdx.x][j];
        }
    }
}

__global__ void red_kernel(const float* __restrict__ part, const float* __restrict__ g,
                           const float* __restrict__ bb, float* __restrict__ A,
                           float* __restrict__ B, int C, int N) {
    int c = blockIdx.x;
    __shared__ float ls[256], lq[256];
    ls[threadIdx.x] = part[(ll)threadIdx.x * 2 * C + c];
    lq[threadIdx.x] = part[(ll)threadIdx.x * 2 * C + C + c];
    __syncthreads();
    for (int str = 128; str >= 1; str >>= 1) {
        if (threadIdx.x < str) {
            ls[threadIdx.x] += ls[threadIdx.x + str];
            lq[threadIdx.x] += lq[threadIdx.x + str];
        }
        __syncthreads();
    }
    if (threadIdx.x == 0) {
        float inv = 1.0f / (float)N;
        float mu = ls[0] * inv, var = lq[0] * inv - mu * mu;
        float a = g[c] * rsqrtf(var + 1e-5f);
        A[c] = a; B[c] = bb[c] - mu * a;
    }
}

template<int C>
__global__ void bnrelu_kernel(const short* __restrict__ x, const float* __restrict__ A,
                              const float* __restrict__ B, short* __restrict__ out, int N) {
    constexpr int CPR = C / 8;
    int i = blockIdx.x * 256 + threadIdx.x;
    if (i >= N * CPR) return;
    int r = i / CPR, ch = i - r * CPR;
    short8 v = *(const short8*)(x + (ll)r * C + ch * 8);
    short8 o;
    #pragma unroll
    for (int j = 0; j < 8; ++j) {
        int c = ch * 8 + j;
        float y = fmaf(bf2f(v[j]), A[c], B[c]);
        o[j] = f2bf(y > 0.f ? y : 0.f);
    }
    *(short8*)(out + (ll)r * C + ch * 8) = o;
}

__global__ void outk_kernel(const short* __restrict__ z, const float* __restrict__ A,
                            const float* __restrict__ B, const float* __restrict__ Wout,
                            float* __restrict__ out, int N) {
    __shared__ float w[64], sa[32], sb[32];
    if (threadIdx.x < 64) w[threadIdx.x] = Wout[threadIdx.x];
    if (threadIdx.x < 32) { sa[threadIdx.x] = A[threadIdx.x]; sb[threadIdx.x] = B[threadIdx.x]; }
    __syncthreads();
    int r = blockIdx.x * 256 + threadIdx.x;
    if (r >= N) return;
    const short* zp = z + (ll)r * 32;
    float o0 = 0.f, o1 = 0.f;
    #pragma unroll
    for (int s4 = 0; s4 < 4; ++s4) {
        short8 v = *(const short8*)(zp + s4 * 8);
        #pragma unroll
        for (int j = 0; j < 8; ++j) {
            int c = s4 * 8 + j;
            float y = fmaf(bf2f(v[j]), sa[c], sb[c]);
            y = y > 0.f ? y : 0.f;
            o0 = fmaf(y, w[2*c], o0);
            o1 = fmaf(y, w[2*c+1], o1);
        }
    }
    out[(ll)r * 2]     = o0;
    out[(ll)r * 2 + 1] = o1;
}

extern "C" void kernel_launch(void* const* d_in, const int* in_sizes, int n_in,
                              void* d_out, int out_size, void* d_ws, size_t ws_size,
                              hipStream_t stream) {
    const float* feats = (const float*)d_in[0];
    const float* W1 = (const float*)d_in[1];
    const float* W2 = (const float*)d_in[2];
    const float* W3 = (const float*)d_in[3];
    const float* W4 = (const float*)d_in[4];
    const float* W5 = (const float*)d_in[5];
    const float* Wout = (const float*)d_in[6];
    const float* g1 = (const float*)d_in[7],  *b1 = (const float*)d_in[8];
    const float* g2 = (const float*)d_in[9],  *b2 = (const float*)d_in[10];
    const float* g3 = (const float*)d_in[11], *b3 = (const float*)d_in[12];
    const float* g4 = (const float*)d_in[13], *b4 = (const float*)d_in[14];
    const float* g5 = (const float*)d_in[15], *b5 = (const float*)d_in[16];
    const int* nbr0 = (const int*)d_in[17];
    const int* nbr1 = (const int*)d_in[18];
    const int* nbr2 = (const int*)d_in[19];
    const int* up1_idx = (const int*)d_in[20];
    const int* up1_off = (const int*)d_in[21];
    const int* up0_idx = (const int*)d_in[22];
    const int* up0_off = (const int*)d_in[23];

    const int N0 = in_sizes[0] / 2;
    const int N1 = in_sizes[20];
    const int N2 = in_sizes[19] / 27;

    char* cur = (char*)d_ws;
    auto alloc = [&](size_t bytes) { char* p = cur; cur += (bytes + 255) & ~255ULL; return p; };
    auto cdiv = [](ll a, ll b) { return (int)((a + b - 1) / b); };

    // stats block: 640 floats BN coeffs | zrow @+2560 (512B) | cnt/cur/bases
    float* stats = (float*)alloc(4096);
    float* A1 = stats,       *B1c = stats + 32;
    float* A2 = stats + 64,  *B2c = stats + 128;
    float* A3 = stats + 192, *B3c = stats + 320;
    float* A4 = stats + 448, *B4c = stats + 512;
    float* A5 = stats + 576, *B5c = stats + 608;
    short* zrow  = (short*)((char*)stats + 2560);   // 256 bf16 zeros
    int*   cnt4  = (int*)((char*)stats + 3072);     // 8
    int*   cur4  = (int*)((char*)stats + 3104);     // 8
    int*   cnt5  = (int*)((char*)stats + 3136);     // 8
    int*   cur5  = (int*)((char*)stats + 3168);     // 8
    int*   bas4  = (int*)((char*)stats + 3200);     // 9
    int*   bas5  = (int*)((char*)stats + 3264);     // 9

    float* part = (float*)alloc(256 * 256 * 4);

    size_t zmax = (size_t)N1 * 64;
    if ((size_t)N0 * 32  > zmax) zmax = (size_t)N0 * 32;
    if ((size_t)N2 * 128 > zmax) zmax = (size_t)N2 * 128;
    short* zb  = (short*)alloc(zmax * 2);
    short* e1b = (short*)alloc((size_t)N0 * 32 * 2);
    short* e2b = (short*)alloc((size_t)N1 * 64 * 2);
    short* e3b = (short*)alloc((size_t)N2 * 128 * 2);
    short* d2b = (short*)alloc((size_t)N1 * 64 * 2);
    short* W1t = (short*)alloc(32 * 64 * 2);
    short* W2t = (short*)alloc((size_t)27 * 64 * 32 * 2);
    short* W3t = (short*)alloc((size_t)27 * 128 * 64 * 2);
    short* W4t = (short*)alloc((size_t)8 * 64 * 128 * 2);
    short* W5t = (short*)alloc((size_t)8 * 32 * 64 * 2);

    const int gridL4 = cdiv((ll)N1 + 512, 64);
    const int gridL5 = cdiv((ll)N0 + 512, 64);
    char* pstart = cur;
    int* perm4 = (int*)alloc((size_t)gridL4 * 64 * 4);
    int* kofb4 = (int*)alloc((size_t)gridL4 * 4);
    int* perm5 = (int*)alloc((size_t)gridL5 * 64 * 4);
    int* kofb5 = (int*)alloc((size_t)gridL5 * 4);
    size_t plen = (size_t)(cur - pstart);

    // zero zrow + counters (640B); 0xFF perm/kofb (-1 sentinel)
    hipMemsetAsync((char*)stats + 2560, 0, 640, stream);
    hipMemsetAsync(pstart, 0xFF, plen, stream);

    prep_kernel<<<cdiv(2048 + 55296 + 221184 + 65536 + 16384, 256), 256, 0, stream>>>(
        W1, W2, W3, W4, W5, W1t, W2t, W3t, W4t, W5t);

    // decoder permutation lists (inputs only — build up front)
    dcount_kernel<<<cdiv(N1, 256), 256, 0, stream>>>(up1_off, cnt4, N1);
    dprefix_kernel<<<1, 256, 0, stream>>>(cnt4, bas4, kofb4);
    dscatter_kernel<<<cdiv(N1, 256), 256, 0, stream>>>(up1_off, bas4, cur4, perm4, N1);
    dcount_kernel<<<cdiv(N0, 256), 256, 0, stream>>>(up0_off, cnt5, N0);
    dprefix_kernel<<<1, 256, 0, stream>>>(cnt5, bas5, kofb5);
    dscatter_kernel<<<cdiv(N0, 256), 256, 0, stream>>>(up0_off, bas5, cur5, perm5, N0);

    // L1: conv(2->32)
    c1_kernel<<<cdiv(N0, 64), 256, 0, stream>>>(feats, nbr0, W1t, zb, N0);
    statsp_kernel<32><<<256, 256, 0, stream>>>(zb, part, N0);
    red_kernel<<<32, 256, 0, stream>>>(part, g1, b1, A1, B1c, 32, N0);
    bnrelu_kernel<32><<<cdiv((ll)N0 * 4, 256), 256, 0, stream>>>(zb, A1, B1c, e1b, N0);

    // L2: conv(32->64): 128 rows x 64 cols, RG=2, KB=3
    msconv_kernel<32, 64, 64, 2, 3, 27><<<dim3(cdiv(N1, 128), 1), 256, 0, stream>>>(
        e1b, nbr1, W2t, zrow, zb, N1);
    statsp_kernel<64><<<256, 256, 0, stream>>>(zb, part, N1);
    red_kernel<<<64, 256, 0, stream>>>(part, g2, b2, A2, B2c, 64, N1);
    bnrelu_kernel<64><<<cdiv((ll)N1 * 8, 256), 256, 0, stream>>>(zb, A2, B2c, e2b, N1);

    // L3: conv(64->128): 64 rows x 64 cols (y=2), RG=1, KB=3
    msconv_kernel<64, 128, 64, 1, 3, 27><<<dim3(cdiv(N2, 64), 2), 256, 0, stream>>>(
        e2b, nbr2, W3t, zrow, zb, N2);
    statsp_kernel<128><<<256, 256, 0, stream>>>(zb, part, N2);
    red_kernel<<<128, 256, 0, stream>>>(part, g3, b3, A3, B3c, 128, N2);
    bnrelu_kernel<128><<<cdiv((ll)N2 * 16, 256), 256, 0, stream>>>(zb, A3, B3c, e3b, N2);

    // L4: upconv(128->64) as permuted gather-GEMM
    gdec_kernel<128, 64><<<gridL4, 256, 0, stream>>>(e3b, perm4, kofb4, up1_idx, W4t, zrow, zb);
    statsp_kernel<64><<<256, 256, 0, stream>>>(zb, part, N1);
    red_kernel<<<64, 256, 0, stream>>>(part, g4, b4, A4, B4c, 64, N1);
    bnrelu_kernel<64><<<cdiv((ll)N1 * 8, 256), 256, 0, stream>>>(zb, A4, B4c, d2b, N1);

    // L5: upconv(64->32) as permuted gather-GEMM + fused BN+ReLU+1x1
    gdec_kernel<64, 32><<<gridL5, 256, 0, stream>>>(d2b, perm5, kofb5, up0_idx, W5t, zrow, zb);
    statsp_kernel<32><<<256, 256, 0, stream>>>(zb, part, N0);
    red_kernel<<<32, 256, 0, stream>>>(part, g5, b5, A5, B5c, 32, N0);
    outk_kernel<<<cdiv(N0, 256), 256, 0, stream>>>(zb, A5, B5c, Wout, (float*)d_out, N0);
}